// Round 8
// baseline (160.771 us; speedup 1.0000x reference)
//
#include <hip/hip_runtime.h>
#include <stdint.h>

#define MARGIN 0.3f
#define M 1024
#define NG 32768
#define K 512
#define BM 256
#define BN 256
#define BK 64
#define KT (K / BK)       // 8 k-tiles
#define NTILES (NG / BN)  // 128 n-tiles
#define MTILES (M / BM)   // 4 m-tiles
#define NPART (NTILES * 4)  // 512 partials per row

typedef __attribute__((ext_vector_type(8))) __bf16 bf16x8;
typedef __attribute__((ext_vector_type(4))) float f32x4;
typedef unsigned short ushort_t;
typedef unsigned int uint_t;

#define BAR() __builtin_amdgcn_s_barrier()
#define SGB0() __builtin_amdgcn_sched_barrier(0)
#define WAIT_LGKM(n) asm volatile("s_waitcnt lgkmcnt(" #n ")" ::: "memory")
#define WAIT_VM(n) asm volatile("s_waitcnt vmcnt(" #n ")" ::: "memory")

// ---- f32 -> bf16 (RNE) ----
static __device__ __forceinline__ ushort_t f2bf(float f) {
    uint_t u = __float_as_uint(f);
    u += 0x7FFFu + ((u >> 16) & 1u);
    return (ushort_t)(u >> 16);
}

// exact-grid convert; also zeroes the output scalar (block 0 thread 0)
__global__ __launch_bounds__(256) void cvt_kernel(const float* __restrict__ src,
                                                  ushort_t* __restrict__ dst, int n8,
                                                  float* __restrict__ out_zero) {
    int i = blockIdx.x * 256 + threadIdx.x;
    if (out_zero && i == 0) out_zero[0] = 0.f;
    if (i >= n8) return;
    const float4* s4 = (const float4*)src;
    float4 a = s4[2 * i];
    float4 b = s4[2 * i + 1];
    uint4 o;
    o.x = (uint_t)f2bf(a.x) | ((uint_t)f2bf(a.y) << 16);
    o.y = (uint_t)f2bf(a.z) | ((uint_t)f2bf(a.w) << 16);
    o.z = (uint_t)f2bf(b.x) | ((uint_t)f2bf(b.y) << 16);
    o.w = (uint_t)f2bf(b.z) | ((uint_t)f2bf(b.w) << 16);
    ((uint4*)dst)[i] = o;
}

// ---- async global->LDS, 16B per lane ----
static __device__ __forceinline__ void gload_lds16(const void* gptr, void* lptr) {
    __builtin_amdgcn_global_load_lds(
        (const __attribute__((address_space(1))) uint32_t*)(gptr),
        (__attribute__((address_space(3))) uint32_t*)(uintptr_t)(lptr),
        16, 0, 0);
}

// ---- asm LDS read: lgkmcnt accounting is OURS ----
static __device__ __forceinline__ bf16x8 lds_read_b128(const ushort_t* p) {
    bf16x8 r;
    asm volatile("ds_read_b128 %0, %1"
                 : "=v"(r)
                 : "v"((const __attribute__((address_space(3))) ushort_t*)p));
    return r;
}

// ---- DPP lane-group-of-16 reduction (pure VALU) ----
template <int CTRL>
static __device__ __forceinline__ float dpp_mv(float x) {
    return __int_as_float(__builtin_amdgcn_update_dpp(
        0, __float_as_int(x), CTRL, 0xF, 0xF, true));
}
static __device__ __forceinline__ float red16_min(float x) {
    x = fminf(x, dpp_mv<0xB1>(x));
    x = fminf(x, dpp_mv<0x4E>(x));
    x = fminf(x, dpp_mv<0x141>(x));
    x = fminf(x, dpp_mv<0x140>(x));
    return x;
}
static __device__ __forceinline__ float red16_max(float x) {
    x = fmaxf(x, dpp_mv<0xB1>(x));
    x = fmaxf(x, dpp_mv<0x4E>(x));
    x = fmaxf(x, dpp_mv<0x141>(x));
    x = fmaxf(x, dpp_mv<0x140>(x));
    return x;
}

// ---- fused 256x256 GEMM: 2 LDS buffers, depth-2 prefetch via mid-kt
//      rotation (stage kt+2 into cur after reads retire), counted waits ----
__global__ __launch_bounds__(512, 2) void gemm_kernel(
    const ushort_t* __restrict__ A,   // [1024][512] bf16
    const ushort_t* __restrict__ B,   // [32768][512] bf16
    const int* __restrict__ targets,  // [1024]
    const int* __restrict__ idxv,     // [1024]
    const int* __restrict__ labels,   // [32768]
    float* __restrict__ pos_part,     // [1024][NPART]
    float* __restrict__ neg_part) {   // [1024][NPART]

    __shared__ __align__(16) ushort_t sA[2][BM * BK];   // 2 x 32KB
    __shared__ __align__(16) ushort_t sB[2][BN * BK];   // 2 x 32KB
    __shared__ int t_s[BM];
    __shared__ int i_s[BM];
    __shared__ int l_s[BN];

    const int tid = threadIdx.x;
    const int lane = tid & 63;
    const int w = tid >> 6;    // wave 0..7
    const int wm = w >> 2;     // 0..1
    const int wn = w & 3;      // 0..3
    const int l15 = lane & 15;
    const int lhi = lane >> 4;  // 0..3
    const int bid = blockIdx.x;
    const int ntile = bid & (NTILES - 1);  // same-ntile blocks -> same XCD
    const int mtile = bid >> 7;

    if (tid < BM) {
        t_s[tid] = targets[mtile * BM + tid];
        i_s[tid] = idxv[mtile * BM + tid];
    } else {
        l_s[tid - BM] = labels[ntile * BN + (tid - BM)];
    }

    f32x4 zero = {0.f, 0.f, 0.f, 0.f};
    f32x4 acc[8][4];
#pragma unroll
    for (int a = 0; a < 8; ++a)
#pragma unroll
        for (int b = 0; b < 4; ++b) acc[a][b] = zero;

    // staging: LDS dest LINEAR; global source col-chunk inverse-XOR-swizzled
    const int rstage = tid >> 3;
    const int cstage = (((tid & 7) ^ (rstage & 7)) << 3);
    const ushort_t* Abase = A + (size_t)mtile * BM * K;
    const ushort_t* Bbase = B + (size_t)ntile * BN * K;

    auto stage_half = [&](const ushort_t* g, ushort_t* l) {
        gload_lds16(g + (size_t)rstage * K + cstage, l + w * 512);
        gload_lds16(g + (size_t)(64 + rstage) * K + cstage, l + 4096 + w * 512);
    };
    auto stage_tile = [&](int buf, int kt) {  // 8 gloads
        stage_half(Abase + (size_t)kt * BK, &sA[buf][0]);
        stage_half(Abase + (size_t)kt * BK + (size_t)128 * K, &sA[buf][8192]);
        stage_half(Bbase + (size_t)kt * BK, &sB[buf][0]);
        stage_half(Bbase + (size_t)kt * BK + (size_t)128 * K, &sB[buf][8192]);
    };

    // swizzled fragment reads: element (r, kchunk u) at chunk u ^ (r&7)
    auto readA = [&](int buf, int mf, int kk) -> bf16x8 {
        const int r = wm * 128 + mf * 16 + l15;
        const int u = (kk * 4 + lhi) ^ (r & 7);
        return lds_read_b128(&sA[buf][r * 64 + u * 8]);
    };
    auto readB = [&](int buf, int nf, int kk) -> bf16x8 {
        const int r = wn * 64 + nf * 16 + l15;
        const int u = (kk * 4 + lhi) ^ (r & 7);
        return lds_read_b128(&sB[buf][r * 64 + u * 8]);
    };

    // ---- prologue: tiles 0,1 staged; wait only for tile 0 ----
    stage_tile(0, 0);
    stage_tile(1, 1);
    WAIT_VM(8);   // tile0's 8 landed; tile1's 8 in flight
    BAR();

#pragma unroll 1
    for (int kt = 0; kt < KT; ++kt) {
        const int cur = kt & 1;
        bf16x8 b0[4], a0lo[4], a0hi[4], b1[4], a1lo[4], a1hi[4];

        // issue reads 0-15: b0, a0lo, a0hi, b1 (asm order = retire order)
#pragma unroll
        for (int nf = 0; nf < 4; ++nf) b0[nf] = readB(cur, nf, 0);
#pragma unroll
        for (int mf = 0; mf < 4; ++mf) a0lo[mf] = readA(cur, mf, 0);
#pragma unroll
        for (int mf = 0; mf < 4; ++mf) a0hi[mf] = readA(cur, mf + 4, 0);
#pragma unroll
        for (int nf = 0; nf < 4; ++nf) b1[nf] = readB(cur, nf, 1);

        WAIT_LGKM(8); SGB0();   // b0 + a0lo retired
        __builtin_amdgcn_s_setprio(1);
#pragma unroll
        for (int mf = 0; mf < 4; ++mf)
#pragma unroll
            for (int nf = 0; nf < 4; ++nf)
                acc[mf][nf] = __builtin_amdgcn_mfma_f32_16x16x32_bf16(a0lo[mf], b0[nf], acc[mf][nf], 0, 0, 0);
        __builtin_amdgcn_s_setprio(0);
        SGB0();

#pragma unroll
        for (int mf = 0; mf < 4; ++mf) a1lo[mf] = readA(cur, mf, 1);  // reads 16-19

        WAIT_LGKM(8); SGB0();   // a0hi retired (outstanding: b1 + a1lo)
        __builtin_amdgcn_s_setprio(1);
#pragma unroll
        for (int mf = 0; mf < 4; ++mf)
#pragma unroll
            for (int nf = 0; nf < 4; ++nf)
                acc[mf + 4][nf] = __builtin_amdgcn_mfma_f32_16x16x32_bf16(a0hi[mf], b0[nf], acc[mf + 4][nf], 0, 0, 0);
        __builtin_amdgcn_s_setprio(0);
        SGB0();

#pragma unroll
        for (int mf = 0; mf < 4; ++mf) a1hi[mf] = readA(cur, mf + 4, 1);  // reads 20-23

        WAIT_LGKM(4); SGB0();   // b1 + a1lo retired (outstanding: a1hi)
        __builtin_amdgcn_s_setprio(1);
#pragma unroll
        for (int mf = 0; mf < 4; ++mf)
#pragma unroll
            for (int nf = 0; nf < 4; ++nf)
                acc[mf][nf] = __builtin_amdgcn_mfma_f32_16x16x32_bf16(a1lo[mf], b1[nf], acc[mf][nf], 0, 0, 0);
        __builtin_amdgcn_s_setprio(0);
        SGB0();

        WAIT_LGKM(0); SGB0();   // a1hi retired -> ALL reads of cur done (this wave)

        // mid-kt rotation: after barrier, cur is dead for every wave ->
        // stage tile kt+2 INTO cur; 4th MFMA group covers the issue.
        if (kt + 2 < KT) {
            BAR();
            stage_tile(cur, kt + 2);
        }

        __builtin_amdgcn_s_setprio(1);
#pragma unroll
        for (int mf = 0; mf < 4; ++mf)
#pragma unroll
            for (int nf = 0; nf < 4; ++nf)
                acc[mf + 4][nf] = __builtin_amdgcn_mfma_f32_16x16x32_bf16(a1hi[mf], b1[nf], acc[mf + 4][nf], 0, 0, 0);
        __builtin_amdgcn_s_setprio(0);
        SGB0();

        // end-of-kt: tile kt+1 landed; tile kt+2's 8 loads stay in flight
        if (kt < KT - 1) {
            if (kt + 2 < KT) { WAIT_VM(8); } else { WAIT_VM(0); }
            BAR();
        }
    }

    // ---- epilogue: masked min/max, DPP 16-lane reduce ----
    int labv[4], jv[4];
#pragma unroll
    for (int nf = 0; nf < 4; ++nf) {
        const int cl = wn * 64 + nf * 16 + l15;
        labv[nf] = l_s[cl];
        jv[nf] = ntile * BN + cl;
    }
#pragma unroll
    for (int mf = 0; mf < 8; ++mf) {
#pragma unroll
        for (int r = 0; r < 4; ++r) {
            const int row_l = wm * 128 + mf * 16 + lhi * 4 + r;
            const int tgt = t_s[row_l];
            const int exc = i_s[row_l];
            float pmin = INFINITY, nmax = -INFINITY;
#pragma unroll
            for (int nf = 0; nf < 4; ++nf) {
                const float v = acc[mf][nf][r];
                const bool same = (labv[nf] == tgt);
                pmin = fminf(pmin, (same && (jv[nf] != exc)) ? v : INFINITY);
                nmax = fmaxf(nmax, same ? -INFINITY : v);
            }
            pmin = red16_min(pmin);
            nmax = red16_max(nmax);
            if (l15 == 0) {
                const int row_g = mtile * BM + row_l;
                pos_part[(size_t)row_g * NPART + ntile * 4 + wn] = pmin;
                neg_part[(size_t)row_g * NPART + ntile * 4 + wn] = nmax;
            }
        }
    }
}

// ---- fused finish: per-row min/max over 512 partials -> hinge -> mean ----
__global__ __launch_bounds__(256) void finish_kernel(const float* __restrict__ pos_part,
                                                     const float* __restrict__ neg_part,
                                                     float* __restrict__ out) {
    const int tid = threadIdx.x;
    const int lane = tid & 63;
    const int wv = tid >> 6;
    const int gwave = blockIdx.x * 4 + wv;   // 0..63
    float lsum = 0.f;
#pragma unroll 1
    for (int rr = 0; rr < 16; ++rr) {
        const int row = gwave * 16 + rr;
        const float* pp = pos_part + (size_t)row * NPART;
        const float* nn = neg_part + (size_t)row * NPART;
        float p = INFINITY, nx = -INFINITY;
#pragma unroll
        for (int j = 0; j < 8; ++j) {
            p = fminf(p, pp[lane + j * 64]);
            nx = fmaxf(nx, nn[lane + j * 64]);
        }
#pragma unroll
        for (int s = 1; s < 64; s <<= 1) {
            p = fminf(p, __shfl_xor(p, s, 64));
            nx = fmaxf(nx, __shfl_xor(nx, s, 64));
        }
        const float l = nx - p + MARGIN;
        lsum += l > 0.f ? l : 0.f;
    }
    __shared__ float sb[4];
    if (lane == 0) sb[wv] = lsum;
    __syncthreads();
    if (tid == 0)
        atomicAdd(out, (sb[0] + sb[1] + sb[2] + sb[3]) * (1.0f / (float)M));
}

extern "C" void kernel_launch(void* const* d_in, const int* in_sizes, int n_in,
                              void* d_out, int out_size, void* d_ws, size_t ws_size,
                              hipStream_t stream) {
    const float* inputs = (const float*)d_in[0];     // [1024,512] f32
    const float* features = (const float*)d_in[1];   // [32768,512] f32
    const int* targets = (const int*)d_in[2];        // [1024] i32
    const int* idxv = (const int*)d_in[3];           // [1024] i32
    const int* labels = (const int*)d_in[4];         // [32768] i32

    char* ws = (char*)d_ws;
    ushort_t* A = (ushort_t*)ws;                               // 1 MB
    ushort_t* B = (ushort_t*)(ws + (1u << 20));                // 32 MB
    float* pos_part = (float*)(ws + (1u << 20) + (32u << 20)); // 2 MB
    float* neg_part = pos_part + (size_t)M * NPART;            // 2 MB

    // f32 -> bf16 (exact grids); cvt-A also zeroes the output scalar
    cvt_kernel<<<(NG * K / 8) / 256, 256, 0, stream>>>(features, B, NG * K / 8, nullptr);
    cvt_kernel<<<(M * K / 8) / 256, 256, 0, stream>>>(inputs, A, M * K / 8, (float*)d_out);

    // fused GEMM + masked partial min/max
    gemm_kernel<<<MTILES * NTILES, 512, 0, stream>>>(A, B, targets, idxv, labels,
                                                     pos_part, neg_part);

    // per-row reduce + hinge + mean (atomic)
    finish_kernel<<<16, 256, 0, stream>>>(pos_part, neg_part, (float*)d_out);
}